// Round 13
// baseline (7450.687 us; speedup 1.0000x reference)
//
#include <hip/hip_runtime.h>

#define S 25
#define Q 75
#define FEAT 64
#define HID 128
#define WAY 5
#define NITERS 10
#define LR 0.01f
#define THREADS 512
#define XPAD 68    // X row stride; quarters skewed to banks {0,16,4,20}
#define HPAD 132   // H/Dh row stride
#define W2PAD 132  // W2 row stride

// Butterfly sum over each 4-lane quad via DPP quad_perm (pure VALU, no LDS).
__device__ __forceinline__ float quad_sum(float v) {
    v += __int_as_float(__builtin_amdgcn_update_dpp(0, __float_as_int(v), 0xB1, 0xF, 0xF, true)); // [1,0,3,2]
    v += __int_as_float(__builtin_amdgcn_update_dpp(0, __float_as_int(v), 0x4E, 0xF, 0xF, true)); // [2,3,0,1]
    return v;
}

// forward body as a MACRO (guaranteed inline, W1 scalars never address-taken).
// FULL unroll (R9's exact math order — unroll-N variants failed deterministically,
// R11/R12). Register demand is tamed instead by sched_barrier(0) per iteration:
// a zero-instruction compile-time fence that stops the pre-RA scheduler from
// hoisting all 25 iterations' ds_reads (R9: demand ~235 VGPR -> spill -> 25 GB).
#define FWD() do {                                                          \
    const float bias = sb1[jj];                                             \
    _Pragma("unroll")                                                       \
    for (int i = 0; i < S; ++i) {                                           \
        const float* xp = &sX[i * XPAD + qb];                               \
        const float4 x0 = *(const float4*)(xp + 0);                         \
        const float4 x1 = *(const float4*)(xp + 4);                         \
        const float4 x2 = *(const float4*)(xp + 8);                         \
        const float4 x3 = *(const float4*)(xp + 12);                        \
        float p0 = w00 * x0.x; p0 = fmaf(w01, x0.y, p0);                    \
        p0 = fmaf(w02, x0.z, p0); p0 = fmaf(w03, x0.w, p0);                 \
        float p1 = w04 * x1.x; p1 = fmaf(w05, x1.y, p1);                    \
        p1 = fmaf(w06, x1.z, p1); p1 = fmaf(w07, x1.w, p1);                 \
        float p2 = w08 * x2.x; p2 = fmaf(w09, x2.y, p2);                    \
        p2 = fmaf(w10, x2.z, p2); p2 = fmaf(w11, x2.w, p2);                 \
        float p3 = w12 * x3.x; p3 = fmaf(w13, x3.y, p3);                    \
        p3 = fmaf(w14, x3.z, p3); p3 = fmaf(w15, x3.w, p3);                 \
        float p = (p0 + p1) + (p2 + p3);                                    \
        p = quad_sum(p);                                                    \
        if (g == 0) sH[i * HPAD + jj] = fmaxf(p + bias, 0.f);               \
        __builtin_amdgcn_sched_barrier(0);                                  \
    }                                                                       \
} while (0)

__global__ __launch_bounds__(THREADS, 2)
void episode_kernel(const float* __restrict__ qf,
                    const float* __restrict__ sf,
                    const int* __restrict__ st,
                    const float* __restrict__ W1g,
                    const float* __restrict__ b1g,
                    const float* __restrict__ W2g,
                    const float* __restrict__ b2g,
                    float* __restrict__ outg)
{
    __shared__ __align__(16) float sX[S * XPAD];       //  6.8 KB
    __shared__ __align__(16) float sH[S * HPAD];       // 13.2 KB
    __shared__ __align__(16) float sDh[S * HPAD];      // 13.2 KB
    __shared__ __align__(16) float sW2[WAY * W2PAD];   //  2.6 KB
    __shared__ __align__(16) float sDl[S * 8];         //  0.8 KB
    __shared__ float sb1[HID];
    __shared__ float sb2[8];
    __shared__ int sTgt[S];

    const int e  = blockIdx.x;
    const int t  = threadIdx.x;
    const int g  = t & 3;                         // k-quarter owner in the quad
    const int jj = t >> 2;                        // hidden unit 0..127
    const int qb = (g << 4) + ((g >> 1) << 2);    // quarter base word (banks {0,16,4,20})

    const float* eQ  = qf  + (size_t)e * Q * FEAT;
    const float* eS  = sf  + (size_t)e * S * FEAT;
    const int*   eT  = st  + (size_t)e * S;
    const float* eW1 = W1g + (size_t)e * HID * FEAT;
    const float* eb1 = b1g + (size_t)e * HID;
    const float* eW2 = W2g + (size_t)e * WAY * HID;
    const float* eb2 = b2g + (size_t)e * WAY;
    float*       eO  = outg + (size_t)e * Q * WAY;

    // ---- W1 in NAMED SCALARS: thread (jj,g) owns W1[jj][g*16..g*16+16) ----
    float w00, w01, w02, w03, w04, w05, w06, w07,
          w08, w09, w10, w11, w12, w13, w14, w15;
    {
        const float4 a0 = *(const float4*)&eW1[(t << 4) + 0];
        const float4 a1 = *(const float4*)&eW1[(t << 4) + 4];
        const float4 a2 = *(const float4*)&eW1[(t << 4) + 8];
        const float4 a3 = *(const float4*)&eW1[(t << 4) + 12];
        w00 = a0.x; w01 = a0.y; w02 = a0.z; w03 = a0.w;
        w04 = a1.x; w05 = a1.y; w06 = a1.z; w07 = a1.w;
        w08 = a2.x; w09 = a2.y; w10 = a2.z; w11 = a2.w;
        w12 = a3.x; w13 = a3.y; w14 = a3.z; w15 = a3.w;
    }
    // ---- stage small episode state into LDS ----
    if (t < S * 16) {                      // X: 400 quads, quarter-skewed rows
        const int i = t >> 4, f = t & 15;
        const int q = f >> 2, sub = f & 3;
        *(float4*)&sX[i * XPAD + (q << 4) + ((q >> 1) << 2) + (sub << 2)] =
            *(const float4*)&eS[t << 2];
    }
    if (t < WAY * 32) {                    // W2 into padded rows
        const int w = t >> 5, q = t & 31;
        *(float4*)&sW2[w * W2PAD + (q << 2)] = *(const float4*)&eW2[t << 2];
    }
    if (t < HID) sb1[t] = eb1[t];
    if (t < WAY) sb2[t] = eb2[t];
    if (t < S)   sTgt[t] = eT[t];
    __syncthreads();

    for (int iter = 0; iter < NITERS; ++iter) {
        FWD();
        __syncthreads();

        // ---------- logits + softmax + dlogits (200 threads, 8-lane groups) ----------
        if (t < S * 8) {
            const int li = t >> 3, lw = t & 7;
            float a = -3.0e38f;
            if (lw < WAY) {
                const float* hr = &sH[li * HPAD];
                const float* wr = &sW2[lw * W2PAD];
                a = sb2[lw];
                #pragma unroll 8
                for (int qd = 0; qd < 32; ++qd) {
                    const float4 hv = *(const float4*)&hr[qd << 2];
                    const float4 wv = *(const float4*)&wr[qd << 2];
                    a += hv.x * wv.x + hv.y * wv.y + hv.z * wv.z + hv.w * wv.w;
                }
            }
            float m = a;
            #pragma unroll
            for (int d = 1; d < 8; d <<= 1) m = fmaxf(m, __shfl_xor(m, d, 8));
            const float ev = (lw < WAY) ? __expf(a - m) : 0.f;
            float sum = ev;
            #pragma unroll
            for (int d = 1; d < 8; d <<= 1) sum += __shfl_xor(sum, d, 8);
            if (lw < WAY) {
                const float p = ev / sum;
                sDl[li * 8 + lw] = (p - (sTgt[li] == lw ? 1.f : 0.f)) * (1.f / (float)S);
            }
        }
        __syncthreads();

        // ---------- dh + gW2 + gb2 (all threads; W2 still pre-update) ----------
        float gw2 = 0.f, gw2b = 0.f, gb2 = 0.f;
        {
            const float w2c0 = sW2[0 * W2PAD + jj];
            const float w2c1 = sW2[1 * W2PAD + jj];
            const float w2c2 = sW2[2 * W2PAD + jj];
            const float w2c3 = sW2[3 * W2PAD + jj];
            const float w2c4 = sW2[4 * W2PAD + jj];
            #pragma unroll
            for (int i = 0; i < S; ++i) {
                const float hv  = sH[i * HPAD + jj];
                const float dlg = sDl[i * 8 + g];
                gw2 = fmaf(dlg, hv, gw2);
                if (g == 0) gw2b = fmaf(sDl[i * 8 + 4], hv, gw2b);
                if ((i & 3) == g) {   // this lane owns row i's dh
                    const float4 d4 = *(const float4*)&sDl[i * 8];
                    const float d5 = sDl[i * 8 + 4];
                    const float dv = d4.x * w2c0 + d4.y * w2c1 + d4.z * w2c2 + d4.w * w2c3 + d5 * w2c4;
                    sDh[i * HPAD + jj] = (hv > 0.f) ? dv : 0.f;
                }
                __builtin_amdgcn_sched_barrier(0);
            }
            if (t < WAY) {
                #pragma unroll
                for (int i = 0; i < S; ++i) gb2 += sDl[i * 8 + t];
            }
        }
        __syncthreads();

        // ---------- updates: W2/b2 (LDS), W1 (register scalars), b1 ----------
        sW2[g * W2PAD + jj] -= LR * gw2;
        if (g == 0) sW2[4 * W2PAD + jj] -= LR * gw2b;
        if (t < WAY) sb2[t] -= LR * gb2;
        {
            float b1acc = 0.f;
            #pragma unroll
            for (int i = 0; i < S; ++i) {
                const float dhv = sDh[i * HPAD + jj];
                b1acc += dhv;
                const float nd = -LR * dhv;
                const float* xp = &sX[i * XPAD + qb];
                const float4 x0 = *(const float4*)(xp + 0);
                const float4 x1 = *(const float4*)(xp + 4);
                const float4 x2 = *(const float4*)(xp + 8);
                const float4 x3 = *(const float4*)(xp + 12);
                w00 = fmaf(nd, x0.x, w00); w01 = fmaf(nd, x0.y, w01);
                w02 = fmaf(nd, x0.z, w02); w03 = fmaf(nd, x0.w, w03);
                w04 = fmaf(nd, x1.x, w04); w05 = fmaf(nd, x1.y, w05);
                w06 = fmaf(nd, x1.z, w06); w07 = fmaf(nd, x1.w, w07);
                w08 = fmaf(nd, x2.x, w08); w09 = fmaf(nd, x2.y, w09);
                w10 = fmaf(nd, x2.z, w10); w11 = fmaf(nd, x2.w, w11);
                w12 = fmaf(nd, x3.x, w12); w13 = fmaf(nd, x3.y, w13);
                w14 = fmaf(nd, x3.z, w14); w15 = fmaf(nd, x3.w, w15);
                __builtin_amdgcn_sched_barrier(0);
            }
            if (g == 0) sb1[jj] -= LR * b1acc;
        }
        __syncthreads();
    }

    // ---------- query forward, 3 chunks of 25 rows ----------
    for (int qc = 0; qc < 3; ++qc) {
        if (t < S * 16) {
            const int i = t >> 4, f = t & 15;
            const int q = f >> 2, sub = f & 3;
            *(float4*)&sX[i * XPAD + (q << 4) + ((q >> 1) << 2) + (sub << 2)] =
                *(const float4*)&eQ[qc * (S * FEAT) + (t << 2)];
        }
        __syncthreads();
        FWD();
        __syncthreads();
        if (t < S * 8) {
            const int li = t >> 3, lw = t & 7;
            if (lw < WAY) {
                const float* hr = &sH[li * HPAD];
                const float* wr = &sW2[lw * W2PAD];
                float a = sb2[lw];
                #pragma unroll 8
                for (int qd = 0; qd < 32; ++qd) {
                    const float4 hv = *(const float4*)&hr[qd << 2];
                    const float4 wv = *(const float4*)&wr[qd << 2];
                    a += hv.x * wv.x + hv.y * wv.y + hv.z * wv.z + hv.w * wv.w;
                }
                eO[(qc * S + li) * WAY + lw] = a;
            }
        }
        __syncthreads();   // next chunk's FWD must not overwrite sH while reads pending
    }
}

extern "C" void kernel_launch(void* const* d_in, const int* in_sizes, int n_in,
                              void* d_out, int out_size, void* d_ws, size_t ws_size,
                              hipStream_t stream) {
    const float* qf  = (const float*)d_in[0];
    const float* sf  = (const float*)d_in[1];
    const int*   st  = (const int*)d_in[2];
    const float* W1  = (const float*)d_in[3];
    const float* b1  = (const float*)d_in[4];
    const float* W2  = (const float*)d_in[5];
    const float* b2  = (const float*)d_in[6];
    float* out = (float*)d_out;
    const int n_eps = in_sizes[0] / (Q * FEAT);   // 4000
    hipLaunchKernelGGL(episode_kernel, dim3(n_eps), dim3(THREADS), 0, stream,
                       qf, sf, st, W1, b1, W2, b2, out);
}

// Round 14
// 6826.814 us; speedup vs baseline: 1.0914x; 1.0914x over previous
//
#include <hip/hip_runtime.h>

#define S 25
#define Q 75
#define FEAT 64
#define HID 128
#define WAY 5
#define NITERS 10
#define LR 0.01f
#define THREADS 512
#define XPAD 68    // X row stride; quarters skewed to banks {0,16,4,20}
#define HPAD 132   // H/Dh row stride
#define W2PAD 132  // W2 row stride

// Butterfly sum over each 4-lane quad via DPP quad_perm (pure VALU, no LDS).
__device__ __forceinline__ float quad_sum(float v) {
    v += __int_as_float(__builtin_amdgcn_update_dpp(0, __float_as_int(v), 0xB1, 0xF, 0xF, true)); // [1,0,3,2]
    v += __int_as_float(__builtin_amdgcn_update_dpp(0, __float_as_int(v), 0x4E, 0xF, 0xF, true)); // [2,3,0,1]
    return v;
}

// forward body as a MACRO (guaranteed inline, W1 scalars never address-taken).
// FULL unroll — R9's exact math; unroll-N variants miscompile (R11/R12,
// deterministic absmax 0.678), sched_barrier(0) was a traffic-null (R13).
#define FWD() do {                                                          \
    const float bias = sb1[jj];                                             \
    _Pragma("unroll")                                                       \
    for (int i = 0; i < S; ++i) {                                           \
        const float* xp = &sX[i * XPAD + qb];                               \
        const float4 x0 = *(const float4*)(xp + 0);                         \
        const float4 x1 = *(const float4*)(xp + 4);                         \
        const float4 x2 = *(const float4*)(xp + 8);                         \
        const float4 x3 = *(const float4*)(xp + 12);                        \
        float p0 = w00 * x0.x; p0 = fmaf(w01, x0.y, p0);                    \
        p0 = fmaf(w02, x0.z, p0); p0 = fmaf(w03, x0.w, p0);                 \
        float p1 = w04 * x1.x; p1 = fmaf(w05, x1.y, p1);                    \
        p1 = fmaf(w06, x1.z, p1); p1 = fmaf(w07, x1.w, p1);                 \
        float p2 = w08 * x2.x; p2 = fmaf(w09, x2.y, p2);                    \
        p2 = fmaf(w10, x2.z, p2); p2 = fmaf(w11, x2.w, p2);                 \
        float p3 = w12 * x3.x; p3 = fmaf(w13, x3.y, p3);                    \
        p3 = fmaf(w14, x3.z, p3); p3 = fmaf(w15, x3.w, p3);                 \
        float p = (p0 + p1) + (p2 + p3);                                    \
        p = quad_sum(p);                                                    \
        if (g == 0) sH[i * HPAD + jj] = fmaxf(p + bias, 0.f);               \
    }                                                                       \
} while (0)

// waves_per_eu(2,2): pin min=max occupancy. R7-R13 lesson: __launch_bounds__'s
// 2nd arg is only a MINIMUM-occupancy cap; the allocator still chose 128 VGPR
// (4 waves/EU) and spilled ~90 floats/thread (25 GB scratch). Pinning to
// exactly 2 waves/EU lets it allocate up to 256 VGPR for a ~216-reg demand.
__global__ __attribute__((amdgpu_flat_work_group_size(THREADS, THREADS),
                          amdgpu_waves_per_eu(2, 2)))
void episode_kernel(const float* __restrict__ qf,
                    const float* __restrict__ sf,
                    const int* __restrict__ st,
                    const float* __restrict__ W1g,
                    const float* __restrict__ b1g,
                    const float* __restrict__ W2g,
                    const float* __restrict__ b2g,
                    float* __restrict__ outg)
{
    __shared__ __align__(16) float sX[S * XPAD];       //  6.8 KB
    __shared__ __align__(16) float sH[S * HPAD];       // 13.2 KB
    __shared__ __align__(16) float sDh[S * HPAD];      // 13.2 KB
    __shared__ __align__(16) float sW2[WAY * W2PAD];   //  2.6 KB
    __shared__ __align__(16) float sDl[S * 8];         //  0.8 KB
    __shared__ float sb1[HID];
    __shared__ float sb2[8];
    __shared__ int sTgt[S];

    const int e  = blockIdx.x;
    const int t  = threadIdx.x;
    const int g  = t & 3;                         // k-quarter owner in the quad
    const int jj = t >> 2;                        // hidden unit 0..127
    const int qb = (g << 4) + ((g >> 1) << 2);    // quarter base word (banks {0,16,4,20})

    const float* eQ  = qf  + (size_t)e * Q * FEAT;
    const float* eS  = sf  + (size_t)e * S * FEAT;
    const int*   eT  = st  + (size_t)e * S;
    const float* eW1 = W1g + (size_t)e * HID * FEAT;
    const float* eb1 = b1g + (size_t)e * HID;
    const float* eW2 = W2g + (size_t)e * WAY * HID;
    const float* eb2 = b2g + (size_t)e * WAY;
    float*       eO  = outg + (size_t)e * Q * WAY;

    // ---- W1 in NAMED SCALARS: thread (jj,g) owns W1[jj][g*16..g*16+16) ----
    float w00, w01, w02, w03, w04, w05, w06, w07,
          w08, w09, w10, w11, w12, w13, w14, w15;
    {
        const float4 a0 = *(const float4*)&eW1[(t << 4) + 0];
        const float4 a1 = *(const float4*)&eW1[(t << 4) + 4];
        const float4 a2 = *(const float4*)&eW1[(t << 4) + 8];
        const float4 a3 = *(const float4*)&eW1[(t << 4) + 12];
        w00 = a0.x; w01 = a0.y; w02 = a0.z; w03 = a0.w;
        w04 = a1.x; w05 = a1.y; w06 = a1.z; w07 = a1.w;
        w08 = a2.x; w09 = a2.y; w10 = a2.z; w11 = a2.w;
        w12 = a3.x; w13 = a3.y; w14 = a3.z; w15 = a3.w;
    }
    // ---- stage small episode state into LDS ----
    if (t < S * 16) {                      // X: 400 quads, quarter-skewed rows
        const int i = t >> 4, f = t & 15;
        const int q = f >> 2, sub = f & 3;
        *(float4*)&sX[i * XPAD + (q << 4) + ((q >> 1) << 2) + (sub << 2)] =
            *(const float4*)&eS[t << 2];
    }
    if (t < WAY * 32) {                    // W2 into padded rows
        const int w = t >> 5, q = t & 31;
        *(float4*)&sW2[w * W2PAD + (q << 2)] = *(const float4*)&eW2[t << 2];
    }
    if (t < HID) sb1[t] = eb1[t];
    if (t < WAY) sb2[t] = eb2[t];
    if (t < S)   sTgt[t] = eT[t];
    __syncthreads();

    for (int iter = 0; iter < NITERS; ++iter) {
        FWD();
        __syncthreads();

        // ---------- logits + softmax + dlogits (200 threads, 8-lane groups) ----------
        if (t < S * 8) {
            const int li = t >> 3, lw = t & 7;
            float a = -3.0e38f;
            if (lw < WAY) {
                const float* hr = &sH[li * HPAD];
                const float* wr = &sW2[lw * W2PAD];
                a = sb2[lw];
                #pragma unroll 8
                for (int qd = 0; qd < 32; ++qd) {
                    const float4 hv = *(const float4*)&hr[qd << 2];
                    const float4 wv = *(const float4*)&wr[qd << 2];
                    a += hv.x * wv.x + hv.y * wv.y + hv.z * wv.z + hv.w * wv.w;
                }
            }
            float m = a;
            #pragma unroll
            for (int d = 1; d < 8; d <<= 1) m = fmaxf(m, __shfl_xor(m, d, 8));
            const float ev = (lw < WAY) ? __expf(a - m) : 0.f;
            float sum = ev;
            #pragma unroll
            for (int d = 1; d < 8; d <<= 1) sum += __shfl_xor(sum, d, 8);
            if (lw < WAY) {
                const float p = ev / sum;
                sDl[li * 8 + lw] = (p - (sTgt[li] == lw ? 1.f : 0.f)) * (1.f / (float)S);
            }
        }
        __syncthreads();

        // ---------- dh + gW2 + gb2 (all threads; W2 still pre-update) ----------
        float gw2 = 0.f, gw2b = 0.f, gb2 = 0.f;
        {
            const float w2c0 = sW2[0 * W2PAD + jj];
            const float w2c1 = sW2[1 * W2PAD + jj];
            const float w2c2 = sW2[2 * W2PAD + jj];
            const float w2c3 = sW2[3 * W2PAD + jj];
            const float w2c4 = sW2[4 * W2PAD + jj];
            #pragma unroll
            for (int i = 0; i < S; ++i) {
                const float hv  = sH[i * HPAD + jj];
                const float dlg = sDl[i * 8 + g];
                gw2 = fmaf(dlg, hv, gw2);
                if (g == 0) gw2b = fmaf(sDl[i * 8 + 4], hv, gw2b);
                if ((i & 3) == g) {   // this lane owns row i's dh
                    const float4 d4 = *(const float4*)&sDl[i * 8];
                    const float d5 = sDl[i * 8 + 4];
                    const float dv = d4.x * w2c0 + d4.y * w2c1 + d4.z * w2c2 + d4.w * w2c3 + d5 * w2c4;
                    sDh[i * HPAD + jj] = (hv > 0.f) ? dv : 0.f;
                }
            }
            if (t < WAY) {
                #pragma unroll
                for (int i = 0; i < S; ++i) gb2 += sDl[i * 8 + t];
            }
        }
        __syncthreads();

        // ---------- updates: W2/b2 (LDS), W1 (register scalars), b1 ----------
        sW2[g * W2PAD + jj] -= LR * gw2;
        if (g == 0) sW2[4 * W2PAD + jj] -= LR * gw2b;
        if (t < WAY) sb2[t] -= LR * gb2;
        {
            float b1acc = 0.f;
            #pragma unroll
            for (int i = 0; i < S; ++i) {
                const float dhv = sDh[i * HPAD + jj];
                b1acc += dhv;
                const float nd = -LR * dhv;
                const float* xp = &sX[i * XPAD + qb];
                const float4 x0 = *(const float4*)(xp + 0);
                const float4 x1 = *(const float4*)(xp + 4);
                const float4 x2 = *(const float4*)(xp + 8);
                const float4 x3 = *(const float4*)(xp + 12);
                w00 = fmaf(nd, x0.x, w00); w01 = fmaf(nd, x0.y, w01);
                w02 = fmaf(nd, x0.z, w02); w03 = fmaf(nd, x0.w, w03);
                w04 = fmaf(nd, x1.x, w04); w05 = fmaf(nd, x1.y, w05);
                w06 = fmaf(nd, x1.z, w06); w07 = fmaf(nd, x1.w, w07);
                w08 = fmaf(nd, x2.x, w08); w09 = fmaf(nd, x2.y, w09);
                w10 = fmaf(nd, x2.z, w10); w11 = fmaf(nd, x2.w, w11);
                w12 = fmaf(nd, x3.x, w12); w13 = fmaf(nd, x3.y, w13);
                w14 = fmaf(nd, x3.z, w14); w15 = fmaf(nd, x3.w, w15);
            }
            if (g == 0) sb1[jj] -= LR * b1acc;
        }
        __syncthreads();
    }

    // ---------- query forward, 3 chunks of 25 rows ----------
    for (int qc = 0; qc < 3; ++qc) {
        if (t < S * 16) {
            const int i = t >> 4, f = t & 15;
            const int q = f >> 2, sub = f & 3;
            *(float4*)&sX[i * XPAD + (q << 4) + ((q >> 1) << 2) + (sub << 2)] =
                *(const float4*)&eQ[qc * (S * FEAT) + (t << 2)];
        }
        __syncthreads();
        FWD();
        __syncthreads();
        if (t < S * 8) {
            const int li = t >> 3, lw = t & 7;
            if (lw < WAY) {
                const float* hr = &sH[li * HPAD];
                const float* wr = &sW2[lw * W2PAD];
                float a = sb2[lw];
                #pragma unroll 8
                for (int qd = 0; qd < 32; ++qd) {
                    const float4 hv = *(const float4*)&hr[qd << 2];
                    const float4 wv = *(const float4*)&wr[qd << 2];
                    a += hv.x * wv.x + hv.y * wv.y + hv.z * wv.z + hv.w * wv.w;
                }
                eO[(qc * S + li) * WAY + lw] = a;
            }
        }
        __syncthreads();   // next chunk's FWD must not overwrite sH while reads pending
    }
}

extern "C" void kernel_launch(void* const* d_in, const int* in_sizes, int n_in,
                              void* d_out, int out_size, void* d_ws, size_t ws_size,
                              hipStream_t stream) {
    const float* qf  = (const float*)d_in[0];
    const float* sf  = (const float*)d_in[1];
    const int*   st  = (const int*)d_in[2];
    const float* W1  = (const float*)d_in[3];
    const float* b1  = (const float*)d_in[4];
    const float* W2  = (const float*)d_in[5];
    const float* b2  = (const float*)d_in[6];
    float* out = (float*)d_out;
    const int n_eps = in_sizes[0] / (Q * FEAT);   // 4000
    hipLaunchKernelGGL(episode_kernel, dim3(n_eps), dim3(THREADS), 0, stream,
                       qf, sf, st, W1, b1, W2, b2, out);
}

// Round 15
// 2270.960 us; speedup vs baseline: 3.2809x; 3.0061x over previous
//
#include <hip/hip_runtime.h>

#define S 25
#define Q 75
#define FEAT 64
#define HID 128
#define WAY 5
#define NITERS 10
#define LR 0.01f
#define THREADS 1024
#define XPAD 68    // X row stride (16B aligned)
#define HPAD 132   // H/Dh row stride
#define W2PAD 132  // W2 row stride

// R14 lesson: allocator pinned 128 VGPR regardless of launch_bounds /
// waves_per_eu / sched_barrier; 512thr x 16-float-W1 structure spilled ~25 GB.
// This version: 1024 thr x 8-float-W1 -> true demand ~45 VGPR, spill impossible.
// All S-loops are '#pragma unroll 1' (rolled): unroll-N pragmas miscompiled
// (R11/R12, deterministic absmax 0.678), full unroll inflates pressure (R9).

__global__ __launch_bounds__(THREADS)
void episode_kernel(const float* __restrict__ qf,
                    const float* __restrict__ sf,
                    const int* __restrict__ st,
                    const float* __restrict__ W1g,
                    const float* __restrict__ b1g,
                    const float* __restrict__ W2g,
                    const float* __restrict__ b2g,
                    float* __restrict__ outg)
{
    __shared__ __align__(16) float sX[S * XPAD];       //  6.8 KB
    __shared__ __align__(16) float sH[S * HPAD];       // 13.2 KB
    __shared__ __align__(16) float sDh[S * HPAD];      // 13.2 KB
    __shared__ __align__(16) float sW2[WAY * W2PAD];   //  2.6 KB
    __shared__ __align__(16) float sDl[S * 8];         //  0.8 KB
    __shared__ float sb1[HID];
    __shared__ float sb2[8];
    __shared__ int sTgt[S];

    const int e  = blockIdx.x;
    const int t  = threadIdx.x;
    const int o  = t & 7;          // octant: owns 8 k-values
    const int jj = t >> 3;         // hidden unit 0..127
    const int kb = o << 3;         // k base word within a 64-float row

    const float* eQ  = qf  + (size_t)e * Q * FEAT;
    const float* eS  = sf  + (size_t)e * S * FEAT;
    const int*   eT  = st  + (size_t)e * S;
    const float* eW1 = W1g + (size_t)e * HID * FEAT;
    const float* eb1 = b1g + (size_t)e * HID;
    const float* eW2 = W2g + (size_t)e * WAY * HID;
    const float* eb2 = b2g + (size_t)e * WAY;
    float*       eO  = outg + (size_t)e * Q * WAY;

    // ---- W1 in 8 named scalars: thread (jj,o) owns W1[jj][o*8..o*8+8) ----
    float w00, w01, w02, w03, w04, w05, w06, w07;
    {
        const float4 a0 = *(const float4*)&eW1[(t << 3) + 0];
        const float4 a1 = *(const float4*)&eW1[(t << 3) + 4];
        w00 = a0.x; w01 = a0.y; w02 = a0.z; w03 = a0.w;
        w04 = a1.x; w05 = a1.y; w06 = a1.z; w07 = a1.w;
    }
    // ---- stage small episode state into LDS ----
    if (t < S * 16) {                      // X: 400 quads
        const int i = t >> 4, f = t & 15;
        *(float4*)&sX[i * XPAD + (f << 2)] = *(const float4*)&eS[t << 2];
    }
    if (t < WAY * 32) {                    // W2 padded rows
        const int w = t >> 5, q = t & 31;
        *(float4*)&sW2[w * W2PAD + (q << 2)] = *(const float4*)&eW2[t << 2];
    }
    if (t < HID) sb1[t] = eb1[t];
    if (t < WAY) sb2[t] = eb2[t];
    if (t < S)   sTgt[t] = eT[t];
    __syncthreads();

    // forward: h[i][jj] = relu(b1 + sum_k x[i][k]*W1[jj][k]); 8-lane k-split
#define FWD() do {                                                          \
    const float bias = sb1[jj];                                             \
    _Pragma("unroll 1")                                                     \
    for (int i = 0; i < S; ++i) {                                           \
        const float* xp = &sX[i * XPAD + kb];                               \
        const float4 x0 = *(const float4*)(xp + 0);                         \
        const float4 x1 = *(const float4*)(xp + 4);                         \
        float p0 = w00 * x0.x; p0 = fmaf(w01, x0.y, p0);                    \
        p0 = fmaf(w02, x0.z, p0); p0 = fmaf(w03, x0.w, p0);                 \
        float p1 = w04 * x1.x; p1 = fmaf(w05, x1.y, p1);                    \
        p1 = fmaf(w06, x1.z, p1); p1 = fmaf(w07, x1.w, p1);                 \
        float p = p0 + p1;                                                  \
        p += __shfl_xor(p, 1, 8);                                           \
        p += __shfl_xor(p, 2, 8);                                           \
        p += __shfl_xor(p, 4, 8);                                           \
        if (o == 0) sH[i * HPAD + jj] = fmaxf(p + bias, 0.f);               \
    }                                                                       \
} while (0)

    for (int iter = 0; iter < NITERS; ++iter) {
        FWD();
        __syncthreads();

        // ---------- logits + softmax + dlogits (200 threads, 8-lane groups) ----------
        if (t < S * 8) {
            const int li = t >> 3, lw = t & 7;
            float a = -3.0e38f;
            if (lw < WAY) {
                const float* hr = &sH[li * HPAD];
                const float* wr = &sW2[lw * W2PAD];
                a = sb2[lw];
                #pragma unroll 8
                for (int qd = 0; qd < 32; ++qd) {
                    const float4 hv = *(const float4*)&hr[qd << 2];
                    const float4 wv = *(const float4*)&wr[qd << 2];
                    a += hv.x * wv.x + hv.y * wv.y + hv.z * wv.z + hv.w * wv.w;
                }
            }
            float m = a;
            #pragma unroll
            for (int d = 1; d < 8; d <<= 1) m = fmaxf(m, __shfl_xor(m, d, 8));
            const float ev = (lw < WAY) ? __expf(a - m) : 0.f;
            float sum = ev;
            #pragma unroll
            for (int d = 1; d < 8; d <<= 1) sum += __shfl_xor(sum, d, 8);
            if (lw < WAY) {
                const float p = ev / sum;
                sDl[li * 8 + lw] = (p - (sTgt[li] == lw ? 1.f : 0.f)) * (1.f / (float)S);
            } else {
                sDl[li * 8 + lw] = 0.f;   // slots 5..7 read by phase C lanes o>=5
            }
        }
        __syncthreads();

        // ---------- dh (8-lane butterfly) + gW2 + gb2 ----------
        float gw2 = 0.f, gb2a = 0.f;
        {
            const float w2c = (o < WAY) ? sW2[o * W2PAD + jj] : 0.f;
            #pragma unroll 1
            for (int i = 0; i < S; ++i) {
                const float hv  = sH[i * HPAD + jj];
                const float dlv = sDl[i * 8 + o];
                float part = dlv * w2c;
                part += __shfl_xor(part, 1, 8);
                part += __shfl_xor(part, 2, 8);
                part += __shfl_xor(part, 4, 8);
                if (o == (i & 7)) sDh[i * HPAD + jj] = (hv > 0.f) ? part : 0.f;
                gw2 = fmaf(dlv, hv, gw2);
            }
            if (t < WAY) {
                #pragma unroll 1
                for (int i = 0; i < S; ++i) gb2a += sDl[i * 8 + t];
            }
        }
        __syncthreads();

        // ---------- updates: W2/b2 (LDS), W1 (registers), b1 ----------
        if (o < WAY) sW2[o * W2PAD + jj] -= LR * gw2;
        if (t < WAY) sb2[t] -= LR * gb2a;
        {
            float b1acc = 0.f;
            #pragma unroll 1
            for (int i = 0; i < S; ++i) {
                const float dhv = sDh[i * HPAD + jj];
                b1acc += dhv;
                const float nd = -LR * dhv;
                const float* xp = &sX[i * XPAD + kb];
                const float4 x0 = *(const float4*)(xp + 0);
                const float4 x1 = *(const float4*)(xp + 4);
                w00 = fmaf(nd, x0.x, w00); w01 = fmaf(nd, x0.y, w01);
                w02 = fmaf(nd, x0.z, w02); w03 = fmaf(nd, x0.w, w03);
                w04 = fmaf(nd, x1.x, w04); w05 = fmaf(nd, x1.y, w05);
                w06 = fmaf(nd, x1.z, w06); w07 = fmaf(nd, x1.w, w07);
            }
            if (o == 0) sb1[jj] -= LR * b1acc;
        }
        __syncthreads();
    }

    // ---------- query forward, 3 chunks of 25 rows ----------
    for (int qc = 0; qc < 3; ++qc) {
        if (t < S * 16) {
            const int i = t >> 4, f = t & 15;
            *(float4*)&sX[i * XPAD + (f << 2)] =
                *(const float4*)&eQ[qc * (S * FEAT) + (t << 2)];
        }
        __syncthreads();
        FWD();
        __syncthreads();
        if (t < S * 8) {
            const int li = t >> 3, lw = t & 7;
            if (lw < WAY) {
                const float* hr = &sH[li * HPAD];
                const float* wr = &sW2[lw * W2PAD];
                float a = sb2[lw];
                #pragma unroll 8
                for (int qd = 0; qd < 32; ++qd) {
                    const float4 hv = *(const float4*)&hr[qd << 2];
                    const float4 wv = *(const float4*)&wr[qd << 2];
                    a += hv.x * wv.x + hv.y * wv.y + hv.z * wv.z + hv.w * wv.w;
                }
                eO[(qc * S + li) * WAY + lw] = a;
            }
        }
        __syncthreads();   // next chunk's staging must not overwrite sX/sH early
    }
}

extern "C" void kernel_launch(void* const* d_in, const int* in_sizes, int n_in,
                              void* d_out, int out_size, void* d_ws, size_t ws_size,
                              hipStream_t stream) {
    const float* qf  = (const float*)d_in[0];
    const float* sf  = (const float*)d_in[1];
    const int*   st  = (const int*)d_in[2];
    const float* W1  = (const float*)d_in[3];
    const float* b1  = (const float*)d_in[4];
    const float* W2  = (const float*)d_in[5];
    const float* b2  = (const float*)d_in[6];
    float* out = (float*)d_out;
    const int n_eps = in_sizes[0] / (Q * FEAT);   // 4000
    hipLaunchKernelGGL(episode_kernel, dim3(n_eps), dim3(THREADS), 0, stream,
                       qf, sf, st, W1, b1, W2, b2, out);
}